// Round 4
// baseline (35750.739 us; speedup 1.0000x reference)
//
#include <hip/hip_runtime.h>
#include <math.h>

// ---------------------------------------------------------------------------
// Seq2Seq forward: encoder GRU (400 steps) -> attention decoder (100 steps)
// V=50000 E=H=512 Lin=400 Tout=100 B=64 Lmax=400.
// R4 KEY FIX: all float inputs are FLOAT32 (reference jax defaults), d_out is
// FLOAT32. f32 loaded, converted in-register to bf16 (RNE) for MFMA operands
// only; epilogues/bias/softmax all f32.
// ---------------------------------------------------------------------------

typedef __attribute__((ext_vector_type(8))) short bh8;   // 8 x bf16 = 4 VGPR
typedef __attribute__((ext_vector_type(4))) float fv4;

// round-to-nearest-even f32 -> bf16 bits
__device__ __forceinline__ short f2b(float f) {
    union { float f; unsigned int u; } c;
    c.f = f;
    unsigned int r = (c.u + 0x7fffu + ((c.u >> 16) & 1u)) >> 16;
    return (short)r;
}
// load 8 consecutive f32, convert to bf16x8 fragment
__device__ __forceinline__ bh8 ld8(const float* __restrict__ p) {
    bh8 r;
    #pragma unroll
    for (int j = 0; j < 8; ++j) r[j] = f2b(p[j]);
    return r;
}
__device__ __forceinline__ float sigmf(float x) { return 1.f / (1.f + expf(-x)); }

__device__ __forceinline__ fv4 mfma16(bh8 a, bh8 b, fv4 c) {
    return __builtin_amdgcn_mfma_f32_16x16x32_bf16(a, b, c, 0, 0, 0);
}

// ---------------------------------------------------------------------------
// One GRU step, fused: gi = x@Wih^T, gh = h@Whh^T, gates, h_new.
// x rows: emb (f32, gathered via tok) or dense [64,512] bf16 buffer (c_bf).
// Grid: 32 blocks x 256 thr = 128 waves. Wave = (b-tile 0..3) x (n-tile 0..31).
// MFMA 16x16x32 bf16 layouts (HW-verified, learn_hip m89/m92):
//   A/B frag: lane holds [row=lane&15][k=(lane>>4)*8 + j], j=0..7
//   C/D:      col=lane&15, row=(lane>>4)*4 + reg
// ---------------------------------------------------------------------------
__global__ __launch_bounds__(256) void k_gru_step(
    const float* __restrict__ Af32, const short* __restrict__ Abf16,
    const int* __restrict__ tok,
    const float* __restrict__ Wih, const float* __restrict__ Whh,
    const float* __restrict__ bih, const float* __restrict__ bhh,
    const float* __restrict__ h_in, const short* __restrict__ h_in_bf,
    float* __restrict__ h_out, short* __restrict__ h_out_bf,
    float* __restrict__ enc0_out)
{
    const int tid  = threadIdx.x;
    const int lane = tid & 63;
    const int w    = blockIdx.x * 4 + (tid >> 6);
    const int b0   = (w & 3) * 16;
    const int n0   = (w >> 2) * 16;
    const int l15  = lane & 15;
    const int ko   = lane >> 4;

    const int brow = b0 + l15;
    const int koff = ko * 8;          // this lane's k offset within 32-chunk

    const float* Ap = Af32 ? (Af32 + (long long)(tok ? tok[brow] : brow) * 512 + koff) : nullptr;
    const bh8*  Apb = Abf16 ? (const bh8*)(Abf16 + (long long)brow * 512) + ko : nullptr;
    const bh8*  Hpb = (const bh8*)(h_in_bf + (long long)brow * 512) + ko;
    const float* Wr = Wih + (long long)(n0 + l15) * 512 + koff;
    const float* Wz = Wih + (long long)(n0 + 512 + l15) * 512 + koff;
    const float* Wn = Wih + (long long)(n0 + 1024 + l15) * 512 + koff;
    const float* Ur = Whh + (long long)(n0 + l15) * 512 + koff;
    const float* Uz = Whh + (long long)(n0 + 512 + l15) * 512 + koff;
    const float* Un = Whh + (long long)(n0 + 1024 + l15) * 512 + koff;

    fv4 air = {0.f, 0.f, 0.f, 0.f};
    fv4 aiz = air, ain = air, ahr = air, ahz = air, ahn = air;
    #pragma unroll 4
    for (int kk = 0; kk < 16; ++kk) {
        const bh8 a = Af32 ? ld8(Ap + kk * 32) : Apb[kk * 4];
        const bh8 h = Hpb[kk * 4];
        air = mfma16(a, ld8(Wr + kk * 32), air);
        aiz = mfma16(a, ld8(Wz + kk * 32), aiz);
        ain = mfma16(a, ld8(Wn + kk * 32), ain);
        ahr = mfma16(h, ld8(Ur + kk * 32), ahr);
        ahz = mfma16(h, ld8(Uz + kk * 32), ahz);
        ahn = mfma16(h, ld8(Un + kk * 32), ahn);
    }
    const int n = n0 + l15;
    const float bir = bih[n], biz = bih[n + 512], bin = bih[n + 1024];
    const float bhr = bhh[n], bhz = bhh[n + 512], bhn = bhh[n + 1024];
    #pragma unroll
    for (int r = 0; r < 4; ++r) {
        const int b = b0 + ko * 4 + r;
        const float rr = sigmf(air[r] + bir + ahr[r] + bhr);
        const float zz = sigmf(aiz[r] + biz + ahz[r] + bhz);
        const float nn = tanhf(ain[r] + bin + rr * (ahn[r] + bhn));
        const float hold = h_in[b * 512 + n];
        const float hnew = (1.f - zz) * nn + zz * hold;
        h_out[b * 512 + n] = hnew;
        h_out_bf[b * 512 + n] = f2b(hnew);
        if (enc0_out) enc0_out[b * 512 + n] = hnew;
    }
}

// ---------------------------------------------------------------------------
// Attention: a = softmax([x|h] @ attn_W^T + attn_b); emit a[:,0] only.
// One block per batch row. Pure f32.
// ---------------------------------------------------------------------------
__global__ __launch_bounds__(256) void k_attn(
    const float* __restrict__ emb, const float* __restrict__ h_f32,
    const float* __restrict__ attn_W, const float* __restrict__ attn_b,
    const int* __restrict__ target, int td,
    float* __restrict__ a0_out)
{
    __shared__ float sx[1024];
    __shared__ float sc[400];
    __shared__ float red[256];
    const int b = blockIdx.x;
    const int tid = threadIdx.x;
    const int tok = (td == 0) ? 1 : target[(td - 1) * 64 + b];
    for (int k = tid; k < 512; k += 256) {
        sx[k] = emb[(long long)tok * 512 + k];
        sx[512 + k] = h_f32[b * 512 + k];
    }
    __syncthreads();
    for (int nn = tid; nn < 400; nn += 256) {
        const fv4* wrow = (const fv4*)(attn_W + (long long)nn * 1024);
        float acc = 0.f;
        for (int kc = 0; kc < 256; ++kc) {
            fv4 v = wrow[kc];
            acc += v[0] * sx[kc * 4 + 0] + v[1] * sx[kc * 4 + 1]
                 + v[2] * sx[kc * 4 + 2] + v[3] * sx[kc * 4 + 3];
        }
        sc[nn] = acc + attn_b[nn];
    }
    __syncthreads();
    float m = -1e30f;
    for (int nn = tid; nn < 400; nn += 256) m = fmaxf(m, sc[nn]);
    red[tid] = m;
    __syncthreads();
    for (int s = 128; s > 0; s >>= 1) {
        if (tid < s) red[tid] = fmaxf(red[tid], red[tid + s]);
        __syncthreads();
    }
    m = red[0];
    __syncthreads();
    float ss = 0.f;
    for (int nn = tid; nn < 400; nn += 256) ss += expf(sc[nn] - m);
    red[tid] = ss;
    __syncthreads();
    for (int s = 128; s > 0; s >>= 1) {
        if (tid < s) red[tid] += red[tid + s];
        __syncthreads();
    }
    if (tid == 0) a0_out[b] = expf(sc[0] - m) / red[0];
}

// ---------------------------------------------------------------------------
// Combine: c = relu([x | enc0*a0] @ comb_W^T + comb_b) -> bf16 buffer.
// One block per batch row. Pure f32 math, bf16 store.
// ---------------------------------------------------------------------------
__global__ __launch_bounds__(256) void k_combine(
    const float* __restrict__ emb, const float* __restrict__ enc0,
    const float* __restrict__ a0, const float* __restrict__ comb_W,
    const float* __restrict__ comb_b, const int* __restrict__ target, int td,
    short* __restrict__ c_bf)
{
    __shared__ float sx[1024];
    const int b = blockIdx.x;
    const int tid = threadIdx.x;
    const int tok = (td == 0) ? 1 : target[(td - 1) * 64 + b];
    const float a0b = a0[b];
    for (int k = tid; k < 512; k += 256) {
        sx[k] = emb[(long long)tok * 512 + k];
        sx[512 + k] = enc0[b * 512 + k] * a0b;
    }
    __syncthreads();
    for (int j = tid; j < 512; j += 256) {
        const fv4* wrow = (const fv4*)(comb_W + (long long)j * 1024);
        float acc = 0.f;
        for (int kc = 0; kc < 256; ++kc) {
            fv4 v = wrow[kc];
            acc += v[0] * sx[kc * 4 + 0] + v[1] * sx[kc * 4 + 1]
                 + v[2] * sx[kc * 4 + 2] + v[3] * sx[kc * 4 + 3];
        }
        acc += comb_b[j];
        c_bf[b * 512 + j] = f2b(fmaxf(acc, 0.f));
    }
}

// ---------------------------------------------------------------------------
// Fused output GEMM + online logsumexp partials. No [64,50000] logits buffer.
// Block = 64 vocab cols (4 waves x 16), all 64 batch rows.
// ---------------------------------------------------------------------------
__global__ __launch_bounds__(256) void k_outloss(
    const short* __restrict__ h2bf, const float* __restrict__ outW,
    const float* __restrict__ outb, const int* __restrict__ target,
    float* __restrict__ pm, float* __restrict__ ps, float* __restrict__ tlogit)
{
    __shared__ float sl[64][65];
    const int tid  = threadIdx.x;
    const int lane = tid & 63;
    const int wl   = tid >> 6;
    const int base = blockIdx.x * 64;
    const int n0   = base + wl * 16;
    const int l15  = lane & 15;
    const int ko   = lane >> 4;

    const int v    = n0 + l15;
    const int vcl  = (v < 50000) ? v : 49999;
    const float* Bp = outW + (long long)vcl * 512 + ko * 8;
    const bh8* A0 = (const bh8*)(h2bf + (long long)(0  + l15) * 512) + ko;
    const bh8* A1 = (const bh8*)(h2bf + (long long)(16 + l15) * 512) + ko;
    const bh8* A2 = (const bh8*)(h2bf + (long long)(32 + l15) * 512) + ko;
    const bh8* A3 = (const bh8*)(h2bf + (long long)(48 + l15) * 512) + ko;
    fv4 c0 = {0.f, 0.f, 0.f, 0.f};
    fv4 c1 = c0, c2 = c0, c3 = c0;
    #pragma unroll 4
    for (int kk = 0; kk < 16; ++kk) {
        const bh8 bb = ld8(Bp + kk * 32);
        c0 = mfma16(A0[kk * 4], bb, c0);
        c1 = mfma16(A1[kk * 4], bb, c1);
        c2 = mfma16(A2[kk * 4], bb, c2);
        c3 = mfma16(A3[kk * 4], bb, c3);
    }
    const float bv = outb[vcl];
    const int cc = wl * 16 + l15;
    const bool ok = (v < 50000);
    #pragma unroll
    for (int r = 0; r < 4; ++r) {
        const int row = ko * 4 + r;
        sl[0  + row][cc] = ok ? (c0[r] + bv) : -1e30f;
        sl[16 + row][cc] = ok ? (c1[r] + bv) : -1e30f;
        sl[32 + row][cc] = ok ? (c2[r] + bv) : -1e30f;
        sl[48 + row][cc] = ok ? (c3[r] + bv) : -1e30f;
    }
    __syncthreads();
    if (tid < 64) {
        const int b = tid;
        float m = -1e30f, s = 0.f;
        for (int c = 0; c < 64; ++c) {
            const float x = sl[b][c];
            if (x > m) { s = s * expf(m - x) + 1.f; m = x; }
            else       { s += expf(x - m); }
        }
        pm[blockIdx.x * 64 + b] = m;
        ps[blockIdx.x * 64 + b] = s;
        const int tg = target[b];
        const int rel = tg - base;
        if (rel >= 0 && rel < 64) tlogit[b] = sl[b][rel];
    }
}

// ---------------------------------------------------------------------------
// Reduce 782 per-block logsumexp partials per batch row; accumulate loss.
// ---------------------------------------------------------------------------
__global__ __launch_bounds__(256) void k_lossred(
    const float* __restrict__ pm, const float* __restrict__ ps,
    const float* __restrict__ tlogit, float* __restrict__ loss_acc)
{
    __shared__ float rm[256], rs[256];
    const int b = blockIdx.x;
    const int tid = threadIdx.x;
    float m = -1e30f, s = 0.f;
    for (int i = tid; i < 782; i += 256) {
        const float m2 = pm[i * 64 + b];
        const float s2 = ps[i * 64 + b];
        if (m2 > m) { s = s * expf(m - m2) + s2; m = m2; }
        else        { s += s2 * expf(m2 - m); }
    }
    rm[tid] = m; rs[tid] = s;
    __syncthreads();
    for (int st = 128; st > 0; st >>= 1) {
        if (tid < st) {
            const float m2 = rm[tid + st], s2 = rs[tid + st];
            const float M = fmaxf(rm[tid], m2);
            rs[tid] = rs[tid] * expf(rm[tid] - M) + s2 * expf(m2 - M);
            rm[tid] = M;
        }
        __syncthreads();
    }
    if (tid == 0) {
        const float logp = tlogit[b] - (rm[0] + logf(rs[0]));
        atomicAdd(loss_acc, -logp * (1.f / 64.f));
    }
}

__global__ void k_init(float* h_f32_0, short* h_bf_0, float* loss_acc)
{
    const int i = blockIdx.x * 256 + threadIdx.x;
    if (i < 64 * 512) { h_f32_0[i] = 0.f; h_bf_0[i] = 0; }
    if (i == 0) *loss_acc = 0.f;
}

__global__ void k_final(const float* loss_acc, float* out)
{
    out[0] = *loss_acc;
}

extern "C" void kernel_launch(void* const* d_in, const int* in_sizes, int n_in,
                              void* d_out, int out_size, void* d_ws, size_t ws_size,
                              hipStream_t stream)
{
    const float* emb     = (const float*)d_in[0];
    const float* enc_Wih = (const float*)d_in[1];
    const float* enc_Whh = (const float*)d_in[2];
    const float* enc_bih = (const float*)d_in[3];
    const float* enc_bhh = (const float*)d_in[4];
    const float* attn_W  = (const float*)d_in[5];
    const float* attn_b  = (const float*)d_in[6];
    const float* comb_W  = (const float*)d_in[7];
    const float* comb_b  = (const float*)d_in[8];
    const float* dec_Wih = (const float*)d_in[9];
    const float* dec_Whh = (const float*)d_in[10];
    const float* dec_bih = (const float*)d_in[11];
    const float* dec_bhh = (const float*)d_in[12];
    const float* out_W   = (const float*)d_in[13];
    const float* out_b   = (const float*)d_in[14];
    const int*   input_t = (const int*)d_in[15];
    const int*   target_t= (const int*)d_in[16];

    char* ws = (char*)d_ws;
    float* h_f32  = (float*)(ws + 0);        // 2 x [64,512] f32      (262144 B)
    float* enc0   = (float*)(ws + 262144);   // [64,512] f32          (131072 B)
    short* h_bf   = (short*)(ws + 393216);   // 2 x [64,512] bf16     (131072 B)
    short* c_bf   = (short*)(ws + 524288);   // [64,512] bf16         ( 65536 B)
    float* a0     = (float*)(ws + 589824);   // [64] f32
    float* lacc   = (float*)(ws + 590336);   // scalar f32
    float* pm     = (float*)(ws + 590592);   // [782,64] f32          (200192 B)
    float* ps     = (float*)(ws + 790784);   // [782,64] f32          (200192 B)
    float* tlog   = (float*)(ws + 990976);   // [64] f32
    // total < 1 MB

    k_init<<<128, 256, 0, stream>>>(h_f32, h_bf, lacc);

    // ---- encoder: 400 sequential fused GRU steps ----
    for (int t = 0; t < 400; ++t) {
        const float* hi  = h_f32 + (t & 1) * 32768;
        const short* hib = h_bf  + (t & 1) * 32768;
        float* ho  = h_f32 + ((t + 1) & 1) * 32768;
        short* hob = h_bf  + ((t + 1) & 1) * 32768;
        k_gru_step<<<32, 256, 0, stream>>>(
            emb, nullptr, input_t + t * 64,
            enc_Wih, enc_Whh, enc_bih, enc_bhh,
            hi, hib, ho, hob, (t == 0) ? enc0 : nullptr);
    }
    // final encoder hidden lands in parity 0 (400 & 1 == 0)

    // ---- decoder: 100 sequential steps ----
    for (int td = 0; td < 100; ++td) {
        const float* hi  = h_f32 + (td & 1) * 32768;
        const short* hib = h_bf  + (td & 1) * 32768;
        float* ho  = h_f32 + ((td + 1) & 1) * 32768;
        short* hob = h_bf  + ((td + 1) & 1) * 32768;
        k_attn<<<64, 256, 0, stream>>>(emb, hi, attn_W, attn_b, target_t, td, a0);
        k_combine<<<64, 256, 0, stream>>>(emb, enc0, a0, comb_W, comb_b,
                                          target_t, td, c_bf);
        k_gru_step<<<32, 256, 0, stream>>>(
            nullptr, c_bf, nullptr,
            dec_Wih, dec_Whh, dec_bih, dec_bhh,
            hi, hib, ho, hob, nullptr);
        k_outloss<<<782, 256, 0, stream>>>(hob, out_W, out_b,
                                           target_t + td * 64, pm, ps, tlog);
        k_lossred<<<64, 256, 0, stream>>>(pm, ps, tlog, lacc);
    }

    k_final<<<1, 1, 0, stream>>>(lacc, (float*)d_out);
}

// Round 5
// 28920.303 us; speedup vs baseline: 1.2362x; 1.2362x over previous
//
#include <hip/hip_runtime.h>
#include <math.h>

// ---------------------------------------------------------------------------
// Seq2Seq forward. V=50000 E=H=512 Lin=400 Tout=100 B=64 Lmax=400.
// R5: (1) persistent encoder kernel (1 launch, atomic grid barrier, 32 blocks
// co-resident), (2) one-time bf16 weight pre-conversion (tiered on ws_size,
// f32 fallback paths kept), (3) fused attn+combine.
// ---------------------------------------------------------------------------

typedef __attribute__((ext_vector_type(8))) short bh8;   // 8 x bf16 = 4 VGPR
typedef __attribute__((ext_vector_type(4))) float fv4;

__device__ __forceinline__ float b2f(short u) {
    union { unsigned int i; float f; } c;
    c.i = ((unsigned int)(unsigned short)u) << 16;
    return c.f;
}
// round-to-nearest-even f32 -> bf16 bits
__device__ __forceinline__ short f2b(float f) {
    union { float f; unsigned int u; } c;
    c.f = f;
    unsigned int r = (c.u + 0x7fffu + ((c.u >> 16) & 1u)) >> 16;
    return (short)r;
}
// load 8 consecutive f32, convert to bf16x8 fragment
__device__ __forceinline__ bh8 ld8(const float* __restrict__ p) {
    bh8 r;
    #pragma unroll
    for (int j = 0; j < 8; ++j) r[j] = f2b(p[j]);
    return r;
}
__device__ __forceinline__ float sigmf(float x) { return 1.f / (1.f + expf(-x)); }

__device__ __forceinline__ fv4 mfma16(bh8 a, bh8 b, fv4 c) {
    return __builtin_amdgcn_mfma_f32_16x16x32_bf16(a, b, c, 0, 0, 0);
}

// Grid barrier: monotone counter, agent-scope acq_rel. All blocks co-resident
// (grid=32 <= 256 CUs). __syncthreads drains each wave's stores (vmcnt(0)
// before s_barrier); release add write-backs XCD L2; acquire spin invalidates.
__device__ __forceinline__ void gridbar(unsigned int* bar, unsigned int target) {
    __syncthreads();
    if (threadIdx.x == 0) {
        __hip_atomic_fetch_add(bar, 1u, __ATOMIC_ACQ_REL, __HIP_MEMORY_SCOPE_AGENT);
        while (__hip_atomic_load(bar, __ATOMIC_ACQUIRE, __HIP_MEMORY_SCOPE_AGENT) < target) {
            __builtin_amdgcn_s_sleep(2);
        }
    }
    __syncthreads();
}

// f32 -> bf16 bulk convert (n multiple of 4; grid = n/1024 blocks)
__global__ __launch_bounds__(256) void k_cvt(
    const float* __restrict__ s, short* __restrict__ d, int n)
{
    const int i = (blockIdx.x * 256 + threadIdx.x) * 4;
    if (i + 3 < n) {
        fv4 v = *(const fv4*)(s + i);
        short4 o;
        o.x = f2b(v[0]); o.y = f2b(v[1]); o.z = f2b(v[2]); o.w = f2b(v[3]);
        *(short4*)(d + i) = o;
    }
}

// ---------------------------------------------------------------------------
// Persistent encoder: all 400 GRU steps in one launch. 32 blocks x 256 thr.
// Block = n-strip (n0 = blockIdx*16); wave = b-tile (b0 = wave*16).
// Weights: bf16 packed [Wih(1536x512); Whh(1536x512)] if Wb!=null, else f32.
// MFMA 16x16x32 bf16 (HW-verified m89/m92): A/B frag lane=[row=lane&15]
// [k=(lane>>4)*8+j]; C/D col=lane&15, row=(lane>>4)*4+reg.
// ---------------------------------------------------------------------------
__global__ __launch_bounds__(256) void k_enc_persist(
    const float* __restrict__ emb, const int* __restrict__ input_t,
    const short* __restrict__ Wb,
    const float* __restrict__ Wih_f, const float* __restrict__ Whh_f,
    const float* __restrict__ bih, const float* __restrict__ bhh,
    float* __restrict__ h_f32, short* __restrict__ h_bf,
    float* __restrict__ enc0, unsigned int* __restrict__ bar)
{
    const int tid  = threadIdx.x;
    const int lane = tid & 63;
    const int wv   = tid >> 6;            // b-tile index 0..3
    const int n0   = blockIdx.x * 16;     // n-strip
    const int b0   = wv * 16;
    const int l15  = lane & 15;
    const int ko   = lane >> 4;
    const int koff = ko * 8;
    const int brow = b0 + l15;
    const int n    = n0 + l15;

    // zero h parity 0 (f32 + bf16)
    for (int i = blockIdx.x * 256 + tid; i < 64 * 512; i += 32 * 256) {
        h_f32[i] = 0.f; h_bf[i] = 0;
    }
    gridbar(bar, 32u);

    // weight pointers (row-major [rows,512], B^T-friendly)
    const bh8 *Wrb = nullptr, *Wzb = nullptr, *Wnb = nullptr;
    const bh8 *Urb = nullptr, *Uzb = nullptr, *Unb = nullptr;
    const float *Wrf = nullptr, *Wzf = nullptr, *Wnf = nullptr;
    const float *Urf = nullptr, *Uzf = nullptr, *Unf = nullptr;
    if (Wb) {
        Wrb = (const bh8*)(Wb + (long long)(n + 0)    * 512) + ko;
        Wzb = (const bh8*)(Wb + (long long)(n + 512)  * 512) + ko;
        Wnb = (const bh8*)(Wb + (long long)(n + 1024) * 512) + ko;
        Urb = (const bh8*)(Wb + (long long)(n + 1536) * 512) + ko;
        Uzb = (const bh8*)(Wb + (long long)(n + 2048) * 512) + ko;
        Unb = (const bh8*)(Wb + (long long)(n + 2560) * 512) + ko;
    } else {
        Wrf = Wih_f + (long long)(n + 0)    * 512 + koff;
        Wzf = Wih_f + (long long)(n + 512)  * 512 + koff;
        Wnf = Wih_f + (long long)(n + 1024) * 512 + koff;
        Urf = Whh_f + (long long)(n + 0)    * 512 + koff;
        Uzf = Whh_f + (long long)(n + 512)  * 512 + koff;
        Unf = Whh_f + (long long)(n + 1024) * 512 + koff;
    }
    const float bir = bih[n], biz = bih[n + 512], bin = bih[n + 1024];
    const float bhr = bhh[n], bhz = bhh[n + 512], bhn = bhh[n + 1024];

    for (int t = 0; t < 400; ++t) {
        const float* hi  = h_f32 + (t & 1) * 32768;
        const short* hib = h_bf  + (t & 1) * 32768;
        float* ho  = h_f32 + ((t + 1) & 1) * 32768;
        short* hob = h_bf  + ((t + 1) & 1) * 32768;

        const int tok = input_t[t * 64 + brow];
        const float* Ap = emb + (long long)tok * 512 + koff;
        const bh8*  Hp  = (const bh8*)(hib + (long long)brow * 512) + ko;

        fv4 air = {0.f, 0.f, 0.f, 0.f};
        fv4 aiz = air, ain = air, ahr = air, ahz = air, ahn = air;
        if (Wb) {
            #pragma unroll 4
            for (int kk = 0; kk < 16; ++kk) {
                const bh8 a = ld8(Ap + kk * 32);
                const bh8 h = Hp[kk * 4];
                air = mfma16(a, Wrb[kk * 4], air);
                aiz = mfma16(a, Wzb[kk * 4], aiz);
                ain = mfma16(a, Wnb[kk * 4], ain);
                ahr = mfma16(h, Urb[kk * 4], ahr);
                ahz = mfma16(h, Uzb[kk * 4], ahz);
                ahn = mfma16(h, Unb[kk * 4], ahn);
            }
        } else {
            #pragma unroll 4
            for (int kk = 0; kk < 16; ++kk) {
                const bh8 a = ld8(Ap + kk * 32);
                const bh8 h = Hp[kk * 4];
                air = mfma16(a, ld8(Wrf + kk * 32), air);
                aiz = mfma16(a, ld8(Wzf + kk * 32), aiz);
                ain = mfma16(a, ld8(Wnf + kk * 32), ain);
                ahr = mfma16(h, ld8(Urf + kk * 32), ahr);
                ahz = mfma16(h, ld8(Uzf + kk * 32), ahz);
                ahn = mfma16(h, ld8(Unf + kk * 32), ahn);
            }
        }
        #pragma unroll
        for (int r = 0; r < 4; ++r) {
            const int b = b0 + ko * 4 + r;
            const float rr = sigmf(air[r] + bir + ahr[r] + bhr);
            const float zz = sigmf(aiz[r] + biz + ahz[r] + bhz);
            const float nn = tanhf(ain[r] + bin + rr * (ahn[r] + bhn));
            const float hold = hi[b * 512 + n];
            const float hnew = (1.f - zz) * nn + zz * hold;
            ho[b * 512 + n] = hnew;
            hob[b * 512 + n] = f2b(hnew);
            if (t == 0) enc0[b * 512 + n] = hnew;
        }
        gridbar(bar, 32u * (t + 2));
    }
}

// ---------------------------------------------------------------------------
// Decoder GRU single step: A = c_bf (bf16), weights bf16 packed or f32.
// 32 blocks x 4 waves; wave = (b-tile, n-tile) as R4.
// ---------------------------------------------------------------------------
__global__ __launch_bounds__(256) void k_gru1(
    const short* __restrict__ c_bf, const short* __restrict__ Wb,
    const float* __restrict__ Wih_f, const float* __restrict__ Whh_f,
    const float* __restrict__ bih, const float* __restrict__ bhh,
    const float* __restrict__ hi, const short* __restrict__ hib,
    float* __restrict__ ho, short* __restrict__ hob)
{
    const int tid  = threadIdx.x;
    const int lane = tid & 63;
    const int w    = blockIdx.x * 4 + (tid >> 6);
    const int b0   = (w & 3) * 16;
    const int n0   = (w >> 2) * 16;
    const int l15  = lane & 15;
    const int ko   = lane >> 4;
    const int koff = ko * 8;
    const int brow = b0 + l15;
    const int n    = n0 + l15;

    const bh8* Ap = (const bh8*)(c_bf + (long long)brow * 512) + ko;
    const bh8* Hp = (const bh8*)(hib + (long long)brow * 512) + ko;

    fv4 air = {0.f, 0.f, 0.f, 0.f};
    fv4 aiz = air, ain = air, ahr = air, ahz = air, ahn = air;
    if (Wb) {
        const bh8* Wr = (const bh8*)(Wb + (long long)(n + 0)    * 512) + ko;
        const bh8* Wz = (const bh8*)(Wb + (long long)(n + 512)  * 512) + ko;
        const bh8* Wn = (const bh8*)(Wb + (long long)(n + 1024) * 512) + ko;
        const bh8* Ur = (const bh8*)(Wb + (long long)(n + 1536) * 512) + ko;
        const bh8* Uz = (const bh8*)(Wb + (long long)(n + 2048) * 512) + ko;
        const bh8* Un = (const bh8*)(Wb + (long long)(n + 2560) * 512) + ko;
        #pragma unroll 4
        for (int kk = 0; kk < 16; ++kk) {
            const bh8 a = Ap[kk * 4];
            const bh8 h = Hp[kk * 4];
            air = mfma16(a, Wr[kk * 4], air);
            aiz = mfma16(a, Wz[kk * 4], aiz);
            ain = mfma16(a, Wn[kk * 4], ain);
            ahr = mfma16(h, Ur[kk * 4], ahr);
            ahz = mfma16(h, Uz[kk * 4], ahz);
            ahn = mfma16(h, Un[kk * 4], ahn);
        }
    } else {
        const float* Wr = Wih_f + (long long)(n + 0)    * 512 + koff;
        const float* Wz = Wih_f + (long long)(n + 512)  * 512 + koff;
        const float* Wn = Wih_f + (long long)(n + 1024) * 512 + koff;
        const float* Ur = Whh_f + (long long)(n + 0)    * 512 + koff;
        const float* Uz = Whh_f + (long long)(n + 512)  * 512 + koff;
        const float* Un = Whh_f + (long long)(n + 1024) * 512 + koff;
        #pragma unroll 4
        for (int kk = 0; kk < 16; ++kk) {
            const bh8 a = Ap[kk * 4];
            const bh8 h = Hp[kk * 4];
            air = mfma16(a, ld8(Wr + kk * 32), air);
            aiz = mfma16(a, ld8(Wz + kk * 32), aiz);
            ain = mfma16(a, ld8(Wn + kk * 32), ain);
            ahr = mfma16(h, ld8(Ur + kk * 32), ahr);
            ahz = mfma16(h, ld8(Uz + kk * 32), ahz);
            ahn = mfma16(h, ld8(Un + kk * 32), ahn);
        }
    }
    const float bir = bih[n], biz = bih[n + 512], bin = bih[n + 1024];
    const float bhr = bhh[n], bhz = bhh[n + 512], bhn = bhh[n + 1024];
    #pragma unroll
    for (int r = 0; r < 4; ++r) {
        const int b = b0 + ko * 4 + r;
        const float rr = sigmf(air[r] + bir + ahr[r] + bhr);
        const float zz = sigmf(aiz[r] + biz + ahz[r] + bhz);
        const float nn = tanhf(ain[r] + bin + rr * (ahn[r] + bhn));
        const float hold = hi[b * 512 + n];
        const float hnew = (1.f - zz) * nn + zz * hold;
        ho[b * 512 + n] = hnew;
        hob[b * 512 + n] = f2b(hnew);
    }
}

// ---------------------------------------------------------------------------
// Fused attention + combine. One block per batch row.
// Phase 1: scores = [x|h]@attn_W^T + attn_b, softmax -> a0 (f32).
// Phase 2: c = relu([x | enc0*a0]@comb_W^T + comb_b) -> bf16.
// ---------------------------------------------------------------------------
__global__ __launch_bounds__(256) void k_attncomb(
    const float* __restrict__ emb, const float* __restrict__ h_f32,
    const float* __restrict__ enc0,
    const float* __restrict__ attn_W, const float* __restrict__ attn_b,
    const float* __restrict__ comb_W, const float* __restrict__ comb_b,
    const int* __restrict__ target, int td, short* __restrict__ c_bf)
{
    __shared__ float sx[1024];
    __shared__ float sc[400];
    __shared__ float red[256];
    __shared__ float a0s;
    const int b = blockIdx.x;
    const int tid = threadIdx.x;
    const int tok = (td == 0) ? 1 : target[(td - 1) * 64 + b];
    for (int k = tid; k < 512; k += 256) {
        sx[k] = emb[(long long)tok * 512 + k];
        sx[512 + k] = h_f32[b * 512 + k];
    }
    __syncthreads();
    for (int nn = tid; nn < 400; nn += 256) {
        const fv4* wrow = (const fv4*)(attn_W + (long long)nn * 1024);
        float acc = 0.f;
        for (int kc = 0; kc < 256; ++kc) {
            fv4 v = wrow[kc];
            acc += v[0] * sx[kc * 4 + 0] + v[1] * sx[kc * 4 + 1]
                 + v[2] * sx[kc * 4 + 2] + v[3] * sx[kc * 4 + 3];
        }
        sc[nn] = acc + attn_b[nn];
    }
    __syncthreads();
    float m = -1e30f;
    for (int nn = tid; nn < 400; nn += 256) m = fmaxf(m, sc[nn]);
    red[tid] = m;
    __syncthreads();
    for (int s = 128; s > 0; s >>= 1) {
        if (tid < s) red[tid] = fmaxf(red[tid], red[tid + s]);
        __syncthreads();
    }
    m = red[0];
    __syncthreads();
    float ss = 0.f;
    for (int nn = tid; nn < 400; nn += 256) ss += expf(sc[nn] - m);
    red[tid] = ss;
    __syncthreads();
    for (int s = 128; s > 0; s >>= 1) {
        if (tid < s) red[tid] += red[tid + s];
        __syncthreads();
    }
    if (tid == 0) a0s = expf(sc[0] - m) / red[0];
    __syncthreads();
    const float a0b = a0s;
    for (int k = tid; k < 512; k += 256) sx[512 + k] = enc0[b * 512 + k] * a0b;
    __syncthreads();
    for (int j = tid; j < 512; j += 256) {
        const fv4* wrow = (const fv4*)(comb_W + (long long)j * 1024);
        float acc = 0.f;
        for (int kc = 0; kc < 256; ++kc) {
            fv4 v = wrow[kc];
            acc += v[0] * sx[kc * 4 + 0] + v[1] * sx[kc * 4 + 1]
                 + v[2] * sx[kc * 4 + 2] + v[3] * sx[kc * 4 + 3];
        }
        acc += comb_b[j];
        c_bf[b * 512 + j] = f2b(fmaxf(acc, 0.f));
    }
}

// ---------------------------------------------------------------------------
// Fused output GEMM + online logsumexp partials. Block = 64 vocab cols.
// out_W from bf16 (outWb) if available, else f32 with in-register convert.
// ---------------------------------------------------------------------------
__global__ __launch_bounds__(256) void k_outloss(
    const short* __restrict__ h2bf,
    const short* __restrict__ outWb, const float* __restrict__ outW,
    const float* __restrict__ outb, const int* __restrict__ target,
    float* __restrict__ pm, float* __restrict__ ps, float* __restrict__ tlogit)
{
    __shared__ float sl[64][65];
    const int tid  = threadIdx.x;
    const int lane = tid & 63;
    const int wl   = tid >> 6;
    const int base = blockIdx.x * 64;
    const int n0   = base + wl * 16;
    const int l15  = lane & 15;
    const int ko   = lane >> 4;

    const int v    = n0 + l15;
    const int vcl  = (v < 50000) ? v : 49999;
    const bh8* A0 = (const bh8*)(h2bf + (long long)(0  + l15) * 512) + ko;
    const bh8* A1 = (const bh8*)(h2bf + (long long)(16 + l15) * 512) + ko;
    const bh8* A2 = (const bh8*)(h2bf + (long long)(32 + l15) * 512) + ko;
    const bh8* A3 = (const bh8*)(h2bf + (long long)(48 + l15) * 512) + ko;
    fv4 c0 = {0.f, 0.f, 0.f, 0.f};
    fv4 c1 = c0, c2 = c0, c3 = c0;
    if (outWb) {
        const bh8* Bp = (const bh8*)(outWb + (long long)vcl * 512) + ko;
        #pragma unroll 4
        for (int kk = 0; kk < 16; ++kk) {
            const bh8 bb = Bp[kk * 4];
            c0 = mfma16(A0[kk * 4], bb, c0);
            c1 = mfma16(A1[kk * 4], bb, c1);
            c2 = mfma16(A2[kk * 4], bb, c2);
            c3 = mfma16(A3[kk * 4], bb, c3);
        }
    } else {
        const float* Bp = outW + (long long)vcl * 512 + ko * 8;
        #pragma unroll 4
        for (int kk = 0; kk < 16; ++kk) {
            const bh8 bb = ld8(Bp + kk * 32);
            c0 = mfma16(A0[kk * 4], bb, c0);
            c1 = mfma16(A1[kk * 4], bb, c1);
            c2 = mfma16(A2[kk * 4], bb, c2);
            c3 = mfma16(A3[kk * 4], bb, c3);
        }
    }
    const float bv = outb[vcl];
    const int cc = wl * 16 + l15;
    const bool ok = (v < 50000);
    #pragma unroll
    for (int r = 0; r < 4; ++r) {
        const int row = ko * 4 + r;
        sl[0  + row][cc] = ok ? (c0[r] + bv) : -1e30f;
        sl[16 + row][cc] = ok ? (c1[r] + bv) : -1e30f;
        sl[32 + row][cc] = ok ? (c2[r] + bv) : -1e30f;
        sl[48 + row][cc] = ok ? (c3[r] + bv) : -1e30f;
    }
    __syncthreads();
    if (tid < 64) {
        const int b = tid;
        float m = -1e30f, s = 0.f;
        for (int c = 0; c < 64; ++c) {
            const float x = sl[b][c];
            if (x > m) { s = s * expf(m - x) + 1.f; m = x; }
            else       { s += expf(x - m); }
        }
        pm[blockIdx.x * 64 + b] = m;
        ps[blockIdx.x * 64 + b] = s;
        const int tg = target[b];
        const int rel = tg - base;
        if (rel >= 0 && rel < 64) tlogit[b] = sl[b][rel];
    }
}

__global__ __launch_bounds__(256) void k_lossred(
    const float* __restrict__ pm, const float* __restrict__ ps,
    const float* __restrict__ tlogit, float* __restrict__ loss_acc)
{
    __shared__ float rm[256], rs[256];
    const int b = blockIdx.x;
    const int tid = threadIdx.x;
    float m = -1e30f, s = 0.f;
    for (int i = tid; i < 782; i += 256) {
        const float m2 = pm[i * 64 + b];
        const float s2 = ps[i * 64 + b];
        if (m2 > m) { s = s * expf(m - m2) + s2; m = m2; }
        else        { s += s2 * expf(m2 - m); }
    }
    rm[tid] = m; rs[tid] = s;
    __syncthreads();
    for (int st = 128; st > 0; st >>= 1) {
        if (tid < st) {
            const float m2 = rm[tid + st], s2 = rs[tid + st];
            const float M = fmaxf(rm[tid], m2);
            rs[tid] = rs[tid] * expf(rm[tid] - M) + s2 * expf(m2 - M);
            rm[tid] = M;
        }
        __syncthreads();
    }
    if (tid == 0) {
        const float logp = tlogit[b] - (rm[0] + logf(rs[0]));
        atomicAdd(loss_acc, -logp * (1.f / 64.f));
    }
}

__global__ void k_init(float* h_f32_0, short* h_bf_0, float* loss_acc,
                       unsigned int* bar)
{
    const int i = blockIdx.x * 256 + threadIdx.x;
    if (i < 64 * 512) { h_f32_0[i] = 0.f; h_bf_0[i] = 0; }
    if (i == 0) { *loss_acc = 0.f; *bar = 0u; }
}

__global__ void k_final(const float* loss_acc, float* out)
{
    out[0] = *loss_acc;
}

extern "C" void kernel_launch(void* const* d_in, const int* in_sizes, int n_in,
                              void* d_out, int out_size, void* d_ws, size_t ws_size,
                              hipStream_t stream)
{
    const float* emb     = (const float*)d_in[0];
    const float* enc_Wih = (const float*)d_in[1];
    const float* enc_Whh = (const float*)d_in[2];
    const float* enc_bih = (const float*)d_in[3];
    const float* enc_bhh = (const float*)d_in[4];
    const float* attn_W  = (const float*)d_in[5];
    const float* attn_b  = (const float*)d_in[6];
    const float* comb_W  = (const float*)d_in[7];
    const float* comb_b  = (const float*)d_in[8];
    const float* dec_Wih = (const float*)d_in[9];
    const float* dec_Whh = (const float*)d_in[10];
    const float* dec_bih = (const float*)d_in[11];
    const float* dec_bhh = (const float*)d_in[12];
    const float* out_W   = (const float*)d_in[13];
    const float* out_b   = (const float*)d_in[14];
    const int*   input_t = (const int*)d_in[15];
    const int*   target_t= (const int*)d_in[16];

    char* ws = (char*)d_ws;
    float* h_f32  = (float*)(ws + 0);          // 2 x [64,512] f32
    float* enc0   = (float*)(ws + 262144);
    short* h_bf   = (short*)(ws + 393216);     // 2 x [64,512] bf16
    short* c_bf   = (short*)(ws + 524288);
    float* lacc   = (float*)(ws + 589824);
    unsigned int* bar = (unsigned int*)(ws + 590080);
    float* pm     = (float*)(ws + 590336);     // [782,64]
    float* ps     = (float*)(ws + 790528);
    float* tlog   = (float*)(ws + 990720);
    short* encWb  = (short*)(ws + 990976);     // 3072x512 bf16 = 3145728 B
    short* decWb  = (short*)(ws + 4136704);    // 3145728 B
    short* outWb  = (short*)(ws + 7282432);    // 25600000 bf16 = 51200000 B

    const bool tier1 = ws_size >= 7282432;     // enc/dec weights bf16
    const bool tier2 = ws_size >= 58482432;    // + out_W bf16

    k_init<<<128, 256, 0, stream>>>(h_f32, h_bf, lacc, bar);

    if (tier1) {
        k_cvt<<<768, 256, 0, stream>>>(enc_Wih, encWb, 786432);
        k_cvt<<<768, 256, 0, stream>>>(enc_Whh, encWb + 786432, 786432);
        k_cvt<<<768, 256, 0, stream>>>(dec_Wih, decWb, 786432);
        k_cvt<<<768, 256, 0, stream>>>(dec_Whh, decWb + 786432, 786432);
    }
    if (tier2) {
        k_cvt<<<25000, 256, 0, stream>>>(out_W, outWb, 25600000);
    }

    // ---- encoder: one persistent launch, 400 steps, grid barrier ----
    k_enc_persist<<<32, 256, 0, stream>>>(
        emb, input_t, tier1 ? encWb : nullptr, enc_Wih, enc_Whh,
        enc_bih, enc_bhh, h_f32, h_bf, enc0, bar);
    // final hidden lands at parity 0 (400 even)

    // ---- decoder: 100 sequential steps x 4 kernels ----
    for (int td = 0; td < 100; ++td) {
        const float* hi  = h_f32 + (td & 1) * 32768;
        const short* hib = h_bf  + (td & 1) * 32768;
        float* ho  = h_f32 + ((td + 1) & 1) * 32768;
        short* hob = h_bf  + ((td + 1) & 1) * 32768;
        k_attncomb<<<64, 256, 0, stream>>>(emb, hi, enc0, attn_W, attn_b,
                                           comb_W, comb_b, target_t, td, c_bf);
        k_gru1<<<32, 256, 0, stream>>>(c_bf, tier1 ? decWb : nullptr,
                                       dec_Wih, dec_Whh, dec_bih, dec_bhh,
                                       hi, hib, ho, hob);
        k_outloss<<<782, 256, 0, stream>>>(hob, tier2 ? outWb : nullptr, out_W,
                                           out_b, target_t + td * 64,
                                           pm, ps, tlog);
        k_lossred<<<64, 256, 0, stream>>>(pm, ps, tlog, lacc);
    }

    k_final<<<1, 1, 0, stream>>>(lacc, (float*)d_out);
}